// Round 8
// baseline (60.430 us; speedup 1.0000x reference)
//
#include <hip/hip_runtime.h>

#define F_   128
#define H_   16
#define E_   32
#define FG   8      // features per wave
#define NWAVES 16   // waves per block -> block covers all 128 features
#define NTHREADS (NWAVES * 64)   // 1024
#define BPB  32     // b rows per block (contiguous)

typedef float v2f __attribute__((ext_vector_type(2)));
typedef float v4f __attribute__((ext_vector_type(4)));

// R6 compute (packed fp32, nt stores, 1-deep x prefetch) with ONE change:
// decomposition. Block = 16 waves = all 128 features; per b the block writes
// one fully-contiguous 16 KB output row, and walks 32 consecutive rows ->
// 512 KB linear write stream per block (fill-kernel-like address locality),
// instead of 1 KB chunks strided by 16 KB from uncorrelated blocks.
__global__ __launch_bounds__(NTHREADS, 4)
void nfe_kernel(const float* __restrict__ x,
                const float* __restrict__ W1,
                const float* __restrict__ b1,
                const float* __restrict__ W2,
                const float* __restrict__ b2,
                float* __restrict__ out)
{
    const int tid  = threadIdx.x;
    const int wave = tid >> 6;
    const int lane = tid & 63;

    const int b0 = blockIdx.x * BPB;

    const int f  = wave * FG + (lane >> 3);
    const int e4 = lane & 7;

    // ---- per-lane weight fragments in registers (as f32 pairs) ----
    v2f w1p[H_/2], b1p[H_/2];
    {
        const v2f* p1 = (const v2f*)(W1 + f * H_);
        const v2f* p2 = (const v2f*)(b1 + f * H_);
#pragma unroll
        for (int q = 0; q < H_/2; ++q) { w1p[q] = p1[q]; b1p[q] = p2[q]; }
    }
    v2f w2p[H_][2];   // [j][e-pair], covers this lane's 4 e's
#pragma unroll
    for (int j = 0; j < H_; ++j) {
        const v2f* q = (const v2f*)(W2 + (f * H_ + j) * E_ + e4 * 4);
        w2p[j][0] = q[0]; w2p[j][1] = q[1];
    }
    v2f b2p[2];
    {
        const v2f* q = (const v2f*)(b2 + f * E_ + e4 * 4);
        b2p[0] = q[0]; b2p[1] = q[1];
    }

    // ---- streaming loop over b: block writes 16 KB contiguous per b ----
    const float* xp = x + (size_t)b0 * F_ + f;
    // float4 index within b-row: f*8 + e4 = wave*64 + lane  (contiguous!)
    v4f* op = (v4f*)out + (size_t)b0 * (F_ * E_ / 4) + tid;

    const v2f zero2 = {0.0f, 0.0f};

    float xv_next = *xp;
#pragma unroll 2
    for (int i = 0; i < BPB; ++i) {
        const float xv = xv_next;
        if (i + 1 < BPB) xv_next = xp[(i + 1) * F_];   // prefetch next b

        // layer 1: h pairs
        v2f x2 = {xv, xv};
        v2f h2[H_/2];
#pragma unroll
        for (int q = 0; q < H_/2; ++q) {
            v2f t = __builtin_elementwise_fma(x2, w1p[q], b1p[q]);
            h2[q] = __builtin_elementwise_max(t, zero2);
        }

        // layer 2: acc pairs, h broadcast via op_sel (lo then hi of h2[q])
        v2f a0 = b2p[0], a1 = b2p[1];
#pragma unroll
        for (int q = 0; q < H_/2; ++q) {
            asm("v_pk_fma_f32 %0, %1, %2, %0 op_sel:[0,0,0] op_sel_hi:[0,1,1]"
                : "+v"(a0) : "v"(h2[q]), "v"(w2p[2*q][0]));
            asm("v_pk_fma_f32 %0, %1, %2, %0 op_sel:[0,0,0] op_sel_hi:[0,1,1]"
                : "+v"(a1) : "v"(h2[q]), "v"(w2p[2*q][1]));
            asm("v_pk_fma_f32 %0, %1, %2, %0 op_sel:[1,0,0] op_sel_hi:[1,1,1]"
                : "+v"(a0) : "v"(h2[q]), "v"(w2p[2*q+1][0]));
            asm("v_pk_fma_f32 %0, %1, %2, %0 op_sel:[1,0,0] op_sel_hi:[1,1,1]"
                : "+v"(a1) : "v"(h2[q]), "v"(w2p[2*q+1][1]));
        }

        v4f acc = {a0.x, a0.y, a1.x, a1.y};
        __builtin_nontemporal_store(acc, op + i * (F_ * E_ / 4));
    }
}

extern "C" void kernel_launch(void* const* d_in, const int* in_sizes, int n_in,
                              void* d_out, int out_size, void* d_ws, size_t ws_size,
                              hipStream_t stream) {
    const float* x  = (const float*)d_in[0];
    const float* W1 = (const float*)d_in[1];
    const float* b1 = (const float*)d_in[2];
    const float* W2 = (const float*)d_in[3];
    const float* b2 = (const float*)d_in[4];
    float* out = (float*)d_out;

    const int B = in_sizes[0] / F_;   // 16384
    dim3 grid(B / BPB);               // 512 blocks, each a 512 KB linear stream
    nfe_kernel<<<grid, NTHREADS, 0, stream>>>(x, W1, b1, W2, b2, out);
}